// Round 6
// baseline (164.205 us; speedup 1.0000x reference)
//
#include <hip/hip_runtime.h>
#include <math.h>

#define NN 500000
#define CH 128
#define NG 1024
#define GRID 256
#define NUNITS ((NN + 63) >> 6)   // 7813 units of 64 rows

typedef __attribute__((ext_vector_type(8))) short short8v;
typedef __attribute__((ext_vector_type(4))) float f32x4;

__device__ __forceinline__ void bf16_split(float f, unsigned short& h, unsigned short& l){
  const unsigned u = __float_as_uint(f);
  h = (unsigned short)(u >> 16);
  const float hif = __uint_as_float(u & 0xffff0000u);
  const float lof = f - hif;
  l = (unsigned short)(__float_as_uint(lof) >> 16);
}

__device__ __forceinline__ void gld_lds16(const void* g, void* l){
  __builtin_amdgcn_global_load_lds(
      (__attribute__((address_space(1))) void*)g,
      (__attribute__((address_space(3))) void*)l, 16, 0, 0);
}

// Prep: (a) t<2048: transpose + bf16-hi/lo-split W1 into Wg (pre-swizzled layout:
// fragment byte = (n*256 + k*2) ^ ((n&7)<<4), hi at 0, lo at +32KB).
// (b) all threads: zero out[NG*CH] and den[NG] (+pad).
__global__ __launch_bounds__(256) void prep_kernel(
    const float* __restrict__ W1, unsigned short* __restrict__ Wg,
    float* __restrict__ out, float* __restrict__ den){
  const int t = blockIdx.x * 256 + threadIdx.x;
  if (t < 2048){
    const int n  = t >> 4;          // out-channel 0..127
    const int k0 = (t & 15) << 3;   // 0,8,...,120
    unsigned short hv[8], lv[8];
    #pragma unroll
    for (int i = 0; i < 8; i++)
      bf16_split(W1[(size_t)(k0 + i) * CH + n], hv[i], lv[i]);
    const int byte = (n * 256 + k0 * 2) ^ ((n & 7) << 4);
    *reinterpret_cast<short8v*>(reinterpret_cast<char*>(Wg) + byte) =
        *reinterpret_cast<short8v*>(hv);
    *reinterpret_cast<short8v*>(reinterpret_cast<char*>(Wg) + 32768 + byte) =
        *reinterpret_cast<short8v*>(lv);
  }
  const float4 z = make_float4(0.f, 0.f, 0.f, 0.f);
  float4* out4 = reinterpret_cast<float4*>(out);
  float4* den4 = reinterpret_cast<float4*>(den);
  const int nthr = gridDim.x * 256;
  for (int i = t; i < 32768 + 256; i += nthr){
    if (i < 32768) out4[i] = z;
    else den4[i - 32768] = z;
  }
}

// Fused: per 64-row unit: stage x to LDS (dbuf, global_load_lds, chunk-swizzled
// source), scores via 3-term bf16-split MFMA (W frags in REGISTERS), e=exp(s),
// then segmented e-weighted pooling from the same LDS tile -> atomics.
__global__ __launch_bounds__(512, 2) void fused_kernel(
    const float* __restrict__ x, const int* __restrict__ batch,
    const unsigned short* __restrict__ Wg,
    const float* __restrict__ b1, const float* __restrict__ w2,
    const float* __restrict__ b2,
    float* __restrict__ out, float* __restrict__ den)
{
  __shared__ char XSc[2 * 32768];   // two 64-row x 128-ch fp32 units
  __shared__ float p4[4][64];       // per-(ch-quarter) partial w2-dots
  __shared__ float es[64];          // exp(score) per row
  __shared__ int   bs[64];          // graph id per row

  const int tid = threadIdx.x;
  const int w   = tid >> 6;     // wave 0..7
  const int l   = tid & 63;
  const int l15 = l & 15;
  const int g   = (l >> 4) & 3;
  const int rw  = w & 1;        // row half (0: rows 0-31, 1: 32-63)
  const int cw  = w >> 1;       // channel quarter 0..3

  const int bid = blockIdx.x;
  const int ntb = (NUNITS - 1 - bid) / GRID + 1;
  const bool is64 = (batch[NN - 1] == 0);   // int64-vs-int32 runtime hedge

  // Per-lane constants
  const float b1v0 = b1[(cw * 2 + 0) * 16 + l15];
  const float b1v1 = b1[(cw * 2 + 1) * 16 + l15];
  const float w2v0 = w2[(cw * 2 + 0) * 16 + l15];
  const float w2v1 = w2[(cw * 2 + 1) * 16 + l15];
  const float b2v  = b2[0];

  // Stage pass p covers rows [p*16, p*16+16) of the unit (8KB per pass).
  auto stage = [&](int uu, int buf, int p0, int p1){
    char* base = XSc + buf * 32768;
    for (int p = p0; p < p1; ++p){
      const int idx = p * 512 + tid;
      const int R = idx >> 5, c = idx & 31;
      int row = uu * 64 + R;
      row = row < NN ? row : NN - 1;      // clamp; es=0 masks contribution
      const char* gsrc = (const char*)x + (size_t)row * 512 + ((c ^ (R & 15)) << 4);
      gld_lds16(gsrc, base + idx * 16);
    }
  };

  // W fragments -> registers (constant across all units). 64 VGPR.
  short8v Bf[2][4][2];
  {
    const char* WgB = (const char*)Wg;
    #pragma unroll
    for (int ctk = 0; ctk < 2; ++ctk){
      const int n = (cw * 2 + ctk) * 16 + l15;
      #pragma unroll
      for (int kc = 0; kc < 4; ++kc){
        const int byte = (n * 256 + kc * 64 + g * 16) ^ ((n & 7) << 4);
        Bf[ctk][kc][0] = *reinterpret_cast<const short8v*>(WgB + byte);
        Bf[ctk][kc][1] = *reinterpret_cast<const short8v*>(WgB + 32768 + byte);
      }
    }
  }

  stage(bid, 0, 0, 4);
  __syncthreads();

  for (int i = 0; i < ntb; ++i){
    const int u = bid + i * GRID;
    const int cur = i & 1, nxt = cur ^ 1;
    const char* xb = XSc + cur * 32768;
    const int unext = u + GRID;

    if (unext < NUNITS) stage(unext, nxt, 0, 3);   // 24KB early

    int bsv = 0;
    if (tid < 64){
      int row = u * 64 + tid;
      row = row < NN ? row : NN - 1;
      bsv = is64 ? batch[2 * row] : batch[row];
    }

    // ---- MFMA: 16 rows x 32 ch per wave, K=128, 3-term bf16 split ----
    f32x4 acc00 = (f32x4)0.f, acc01 = (f32x4)0.f;
    f32x4 acc10 = (f32x4)0.f, acc11 = (f32x4)0.f;
    #pragma unroll
    for (int kc = 0; kc < 4; ++kc){
      const int s0 = kc * 8 + g * 2;
      short8v Ah0, Al0, Ah1, Al1;
      {
        const char* bp = xb + (rw * 32 + l15) * 512;
        float fv[8];
        *reinterpret_cast<float4*>(fv)     = *reinterpret_cast<const float4*>(bp + ((s0 ^ l15) << 4));
        *reinterpret_cast<float4*>(fv + 4) = *reinterpret_cast<const float4*>(bp + (((s0 + 1) ^ l15) << 4));
        unsigned short hv[8], lv[8];
        #pragma unroll
        for (int j = 0; j < 8; j++) bf16_split(fv[j], hv[j], lv[j]);
        Ah0 = *reinterpret_cast<short8v*>(hv); Al0 = *reinterpret_cast<short8v*>(lv);
      }
      {
        const char* bp = xb + (rw * 32 + 16 + l15) * 512;
        float fv[8];
        *reinterpret_cast<float4*>(fv)     = *reinterpret_cast<const float4*>(bp + ((s0 ^ l15) << 4));
        *reinterpret_cast<float4*>(fv + 4) = *reinterpret_cast<const float4*>(bp + (((s0 + 1) ^ l15) << 4));
        unsigned short hv[8], lv[8];
        #pragma unroll
        for (int j = 0; j < 8; j++) bf16_split(fv[j], hv[j], lv[j]);
        Ah1 = *reinterpret_cast<short8v*>(hv); Al1 = *reinterpret_cast<short8v*>(lv);
      }
      acc00 = __builtin_amdgcn_mfma_f32_16x16x32_bf16(Ah0, Bf[0][kc][0], acc00, 0, 0, 0);
      acc00 = __builtin_amdgcn_mfma_f32_16x16x32_bf16(Al0, Bf[0][kc][0], acc00, 0, 0, 0);
      acc00 = __builtin_amdgcn_mfma_f32_16x16x32_bf16(Ah0, Bf[0][kc][1], acc00, 0, 0, 0);
      acc01 = __builtin_amdgcn_mfma_f32_16x16x32_bf16(Ah0, Bf[1][kc][0], acc01, 0, 0, 0);
      acc01 = __builtin_amdgcn_mfma_f32_16x16x32_bf16(Al0, Bf[1][kc][0], acc01, 0, 0, 0);
      acc01 = __builtin_amdgcn_mfma_f32_16x16x32_bf16(Ah0, Bf[1][kc][1], acc01, 0, 0, 0);
      acc10 = __builtin_amdgcn_mfma_f32_16x16x32_bf16(Ah1, Bf[0][kc][0], acc10, 0, 0, 0);
      acc10 = __builtin_amdgcn_mfma_f32_16x16x32_bf16(Al1, Bf[0][kc][0], acc10, 0, 0, 0);
      acc10 = __builtin_amdgcn_mfma_f32_16x16x32_bf16(Ah1, Bf[0][kc][1], acc10, 0, 0, 0);
      acc11 = __builtin_amdgcn_mfma_f32_16x16x32_bf16(Ah1, Bf[1][kc][0], acc11, 0, 0, 0);
      acc11 = __builtin_amdgcn_mfma_f32_16x16x32_bf16(Al1, Bf[1][kc][0], acc11, 0, 0, 0);
      acc11 = __builtin_amdgcn_mfma_f32_16x16x32_bf16(Ah1, Bf[1][kc][1], acc11, 0, 0, 0);
    }

    // ---- partial score dots (relu + w2) -> p4[cw][row] ----
    #pragma unroll
    for (int nt = 0; nt < 2; ++nt){
      const f32x4 a0 = nt ? acc10 : acc00;
      const f32x4 a1 = nt ? acc11 : acc01;
      #pragma unroll
      for (int r = 0; r < 4; ++r){
        float s = fmaxf(a0[r] + b1v0, 0.f) * w2v0;
        s = fmaf(fmaxf(a1[r] + b1v1, 0.f), w2v1, s);
        s += __shfl_xor(s, 1); s += __shfl_xor(s, 2);
        s += __shfl_xor(s, 4); s += __shfl_xor(s, 8);
        if (l15 == 0) p4[cw][rw * 32 + nt * 16 + g * 4 + r] = s;
      }
    }
    if (tid < 64) bs[tid] = bsv;
    __syncthreads();   // B1: p4, bs visible (drains stage passes 0-2 too)

    if (tid < 64){
      const float s = p4[0][tid] + p4[1][tid] + p4[2][tid] + p4[3][tid] + b2v;
      es[tid] = (u * 64 + tid < NN) ? __expf(s) : 0.f;
    }
    __syncthreads();   // B2: es visible

    if (unext < NUNITS) stage(unext, nxt, 3, 4);  // last 8KB covers pooling

    // ---- segmented pooling: 4 threads per channel, 16 rows each ----
    {
      const int c = tid & 127;
      const int q = tid >> 7;
      const bool dden = (c == 0);
      float accp = 0.f, dacc = 0.f;
      int gprev = bs[q * 16];
      for (int rr = 0; rr < 16; ++rr){
        const int r = q * 16 + rr;
        const int gg = bs[r];
        if (gg != gprev){
          atomicAdd(&out[(size_t)gprev * CH + c], accp);
          if (dden) atomicAdd(&den[gprev], dacc);
          accp = 0.f; dacc = 0.f; gprev = gg;
        }
        const float e = es[r];
        const float xv = *reinterpret_cast<const float*>(
            xb + r * 512 + ((((c >> 2) ^ (r & 15)) << 4) | ((c & 3) << 2)));
        accp = fmaf(e, xv, accp);
        if (dden) dacc += e;
      }
      atomicAdd(&out[(size_t)gprev * CH + c], accp);
      if (dden) atomicAdd(&den[gprev], dacc);
    }
    __syncthreads();   // B3: xb free for restage; drains last pass + atomics
  }
}

// Normalize: out[g][c] /= den[g] (0 for empty graphs)
__global__ __launch_bounds__(256) void norm_kernel(
    float* __restrict__ out, const float* __restrict__ den){
  const int idx = blockIdx.x * 256 + threadIdx.x;   // float4 index
  if (idx >= NG * 32) return;
  const int gidx = idx >> 5;
  const float d = den[gidx];
  const float inv = d > 0.f ? 1.f / d : 0.f;
  float4 v = reinterpret_cast<float4*>(out)[idx];
  v.x *= inv; v.y *= inv; v.z *= inv; v.w *= inv;
  reinterpret_cast<float4*>(out)[idx] = v;
}

extern "C" void kernel_launch(void* const* d_in, const int* in_sizes, int n_in,
                              void* d_out, int out_size, void* d_ws, size_t ws_size,
                              hipStream_t stream){
  const float* x    = (const float*)d_in[0];
  const int*   batch= (const int*)d_in[1];
  const float* W1   = (const float*)d_in[2];
  const float* b1   = (const float*)d_in[3];
  const float* w2   = (const float*)d_in[4];
  const float* b2   = (const float*)d_in[5];
  float* out = (float*)d_out;

  unsigned short* Wg = (unsigned short*)d_ws;            // 64KB pre-split W
  float* den = (float*)((char*)d_ws + 65536);            // NG floats (+pad)

  prep_kernel<<<40, 256, 0, stream>>>(W1, Wg, out, den);
  fused_kernel<<<GRID, 512, 0, stream>>>(x, batch, Wg, b1, w2, b2, out, den);
  norm_kernel<<<128, 256, 0, stream>>>(out, den);
}